// Round 5
// baseline (402.740 us; speedup 1.0000x reference)
//
#include <hip/hip_runtime.h>

#define NUM_CODES 1024
#define DIM 32
#define ROWS 131072      // 16384 * 8
#define DECAYF 0.99f
#define EPSF 1e-5f
#define CCOST 0.25f
#define SLAB 33792       // 32768 dw + 1024 counts
#define RGROUPS 8        // reduce stage-1 groups
#define IBLK (SLAB / 256)  // 132
#define CHUNKS 4
#define TILES_PER_CHUNK 16

typedef __attribute__((ext_vector_type(8))) short short8v;
typedef __attribute__((ext_vector_type(4))) float f32x4;

__device__ __forceinline__ unsigned short bf16_rne(float f) {
    unsigned u = __float_as_uint(f);
    unsigned r = u + 0x7FFFu + ((u >> 16) & 1u);
    return (unsigned short)(r >> 16);
}

// ---------------- K0: prep — bf16 hi/lo B tables + negated half norms + loss zero ----
// slot = tile*64 + lane; B-frag layout: col = lane&15 (code within tile),
// k = (lane>>4)*8 + j. Each slot stores 8 bf16 (16 B) in hi and lo tables.
__global__ __launch_bounds__(256) void k_prep(const float* __restrict__ emb,
                                              unsigned short* __restrict__ bhi,
                                              unsigned short* __restrict__ blo,
                                              float* __restrict__ nneg,
                                              float* __restrict__ loss_sum) {
    int s = blockIdx.x * 256 + threadIdx.x;   // 0..4095
    if (s == 0) loss_sum[0] = 0.0f;
    if (s < NUM_CODES) {
        const float4* e4 = (const float4*)(emb + s * DIM);
        float sum = 0.0f;
#pragma unroll
        for (int j = 0; j < 8; ++j) {
            float4 e = e4[j];
            sum += e.x * e.x + e.y * e.y + e.z * e.z + e.w * e.w;
        }
        nneg[s] = -0.5f * sum;
    }
    int l = s & 63, t = s >> 6;
    int code = t * 16 + (l & 15);
    int koff = (l >> 4) * 8;
    const float* src = emb + code * DIM + koff;
    float4 f0 = *(const float4*)(src);
    float4 f1 = *(const float4*)(src + 4);
    float fv[8] = {f0.x, f0.y, f0.z, f0.w, f1.x, f1.y, f1.z, f1.w};
    short8v h, lo;
#pragma unroll
    for (int j = 0; j < 8; ++j) {
        unsigned short hb = bf16_rne(fv[j]);
        float hf = __uint_as_float((unsigned)hb << 16);
        h[j]  = (short)hb;
        lo[j] = (short)bf16_rne(fv[j] - hf);
    }
    *(short8v*)(bhi + (size_t)s * 8) = h;
    *(short8v*)(blo + (size_t)s * 8) = lo;
}

// ---------------- K1: MFMA distance + argmin, codebook split across waves ----------
// Block = 4 waves, all owning the SAME 64 rows (A reads shared via L1);
// wave w scans tiles [w*16, w*16+16). Per-chunk winner packed as
// (order-mapped dist << 32) | code into part[w*ROWS + row]; combined in k_scatter.
// acc init = -0.5||e||^2, 3 MFMAs add hi/lo cross terms => acc = -(dist).
// C/D layout (m89-verified): col = lane&15, row = (lane>>4)*4 + reg.
__global__ __launch_bounds__(256, 8) void k_argmin(const float* __restrict__ flat,
                                                   const unsigned short* __restrict__ bhi_g,
                                                   const unsigned short* __restrict__ blo_g,
                                                   const float* __restrict__ nneg,
                                                   unsigned long long* __restrict__ part) {
    const int lane = threadIdx.x & 63;
    const int wid  = threadIdx.x >> 6;       // chunk 0..3
    const int rowbase = blockIdx.x * 64;
    const int lr = lane & 15;   // A row / B,C col within frag
    const int lg = lane >> 4;   // k-group

    // load + hi/lo split A (4 row-frags, 64 rows)
    short8v ahi[4], alo[4];
#pragma unroll
    for (int rf = 0; rf < 4; ++rf) {
        const float* src = flat + (size_t)(rowbase + rf * 16 + lr) * DIM + lg * 8;
        float4 f0 = *(const float4*)src;
        float4 f1 = *(const float4*)(src + 4);
        float fv[8] = {f0.x, f0.y, f0.z, f0.w, f1.x, f1.y, f1.z, f1.w};
        short8v h, lo;
#pragma unroll
        for (int j = 0; j < 8; ++j) {
            unsigned short hb = bf16_rne(fv[j]);
            float hf = __uint_as_float((unsigned)hb << 16);
            h[j]  = (short)hb;
            lo[j] = (short)bf16_rne(fv[j] - hf);
        }
        ahi[rf] = h; alo[rf] = lo;
    }

    float best[4][4];
    int   bc[4][4];
#pragma unroll
    for (int rf = 0; rf < 4; ++rf)
#pragma unroll
        for (int rg = 0; rg < 4; ++rg) { best[rf][rg] = -3.4e38f; bc[rf][rg] = 0; }

    const int t0 = wid * TILES_PER_CHUNK;
#pragma unroll 2
    for (int tt = 0; tt < TILES_PER_CHUNK; ++tt) {
        const int t = t0 + tt;
        short8v bh = *(const short8v*)(bhi_g + ((size_t)t * 64 + lane) * 8);
        short8v bl = *(const short8v*)(blo_g + ((size_t)t * 64 + lane) * 8);
        float nn = nneg[t * 16 + lr];
        int code = t * 16 + lr;
#pragma unroll
        for (int rf = 0; rf < 4; ++rf) {
            f32x4 acc = {nn, nn, nn, nn};
            acc = __builtin_amdgcn_mfma_f32_16x16x32_bf16(ahi[rf], bh, acc, 0, 0, 0);
            acc = __builtin_amdgcn_mfma_f32_16x16x32_bf16(ahi[rf], bl, acc, 0, 0, 0);
            acc = __builtin_amdgcn_mfma_f32_16x16x32_bf16(alo[rf], bh, acc, 0, 0, 0);
#pragma unroll
            for (int rg = 0; rg < 4; ++rg) {
                // strict > keeps the earliest (smallest) code on exact ties
                if (acc[rg] > best[rf][rg]) { best[rf][rg] = acc[rg]; bc[rf][rg] = code; }
            }
        }
    }

    // argmax reduce across the 16-lane group, pack, write per-chunk winner
#pragma unroll
    for (int rf = 0; rf < 4; ++rf) {
#pragma unroll
        for (int rg = 0; rg < 4; ++rg) {
            float b = best[rf][rg];
            int   c = bc[rf][rg];
#pragma unroll
            for (int m = 1; m < 16; m <<= 1) {
                float b2 = __shfl_xor(b, m);
                int   c2 = __shfl_xor(c, m);
                if (b2 > b || (b2 == b && c2 < c)) { b = b2; c = c2; }
            }
            if (lr == rg) {
                int row = rowbase + rf * 16 + lg * 4 + rg;
                float dist = -b;   // smaller = better
                unsigned du = __float_as_uint(dist);
                du = (du & 0x80000000u) ? ~du : (du | 0x80000000u);
                part[(size_t)wid * ROWS + row] =
                    ((unsigned long long)du << 32) | (unsigned)c;
            }
        }
    }
}

// ---------------- K2: combine argmin, gather/quantize, loss; LDS counts/dw ---------
__global__ __launch_bounds__(256) void k_scatter(const float* __restrict__ flat,
                                                 const float* __restrict__ emb,
                                                 const unsigned long long* __restrict__ part,
                                                 float* __restrict__ qout,
                                                 float* __restrict__ idxf_out,
                                                 float* __restrict__ slabs,
                                                 float* __restrict__ loss_sum,
                                                 int rows_per_block) {
    __shared__ float acc[SLAB];   // 132 KB
    __shared__ float red[256];
    const int tid = threadIdx.x;
    for (int i = tid; i < SLAB; i += 256) acc[i] = 0.0f;
    __syncthreads();

    const int row0 = blockIdx.x * rows_per_block;
    float l = 0.0f;
    for (int rr = 0; rr < rows_per_block; rr += 256) {
        int r = row0 + rr + tid;
        unsigned long long p0 = part[r];
        unsigned long long p1 = part[(size_t)ROWS + r];
        unsigned long long p2 = part[2 * (size_t)ROWS + r];
        unsigned long long p3 = part[3 * (size_t)ROWS + r];
        unsigned long long pm = min(min(p0, p1), min(p2, p3));
        int k = (int)(pm & 0xFFFFFFFFu);
        idxf_out[r] = (float)k;

        const float4* f4 = (const float4*)(flat + (size_t)r * DIM);
        const float4* e4 = (const float4*)(emb + (size_t)k * DIM);
        float4* q4 = (float4*)(qout + (size_t)r * DIM);
        int kb = k * DIM;
#pragma unroll
        for (int j4 = 0; j4 < 8; ++j4) {
            float4 f = f4[j4];
            float4 e = e4[j4];
            q4[j4] = e;
            float dx = e.x - f.x, dy = e.y - f.y, dz = e.z - f.z, dv = e.w - f.w;
            l += dx * dx + dy * dy + dz * dz + dv * dv;
            int j = 4 * j4;
            // swizzled LDS layout: entry (k,j) lives at k*32 + ((j+k)&31)
            atomicAdd(&acc[kb + ((j + 0 + k) & 31)], f.x);
            atomicAdd(&acc[kb + ((j + 1 + k) & 31)], f.y);
            atomicAdd(&acc[kb + ((j + 2 + k) & 31)], f.z);
            atomicAdd(&acc[kb + ((j + 3 + k) & 31)], f.w);
        }
        atomicAdd(&acc[32768 + k], 1.0f);
    }
    __syncthreads();

    // flush LDS -> per-block slab (un-swizzle; coalesced global writes)
    float* slab = slabs + (size_t)blockIdx.x * SLAB;
    for (int i = tid; i < 32768; i += 256) {
        int k = i >> 5, j = i & 31;
        slab[i] = acc[(i & ~31) | ((j + k) & 31)];
    }
    for (int i = tid; i < NUM_CODES; i += 256) slab[32768 + i] = acc[32768 + i];

    red[tid] = l;
    __syncthreads();
    for (int s = 128; s > 0; s >>= 1) {
        if (tid < s) red[tid] += red[tid + s];
        __syncthreads();
    }
    if (tid == 0) atomicAdd(loss_sum, red[0]);
}

// ---------------- K2b: two-stage slab reduction ----------------
__global__ __launch_bounds__(256) void k_reduce1(const float* __restrict__ slabs,
                                                 float* __restrict__ partial,
                                                 int pcount) {
    int g  = blockIdx.x / IBLK;
    int ib = blockIdx.x % IBLK;
    int i = ib * 256 + threadIdx.x;
    const float* base = slabs + (size_t)g * pcount * SLAB + i;
    float s = 0.0f;
#pragma unroll 4
    for (int p = 0; p < pcount; ++p) s += base[(size_t)p * SLAB];
    partial[(size_t)g * SLAB + i] = s;
}

__global__ __launch_bounds__(256) void k_reduce2(const float* __restrict__ partial,
                                                 float* __restrict__ dw_sum,
                                                 float* __restrict__ counts_sum) {
    int i = blockIdx.x * 256 + threadIdx.x;
    float s = 0.0f;
#pragma unroll
    for (int g = 0; g < RGROUPS; ++g) s += partial[(size_t)g * SLAB + i];
    if (i < 32768) dw_sum[i] = s;
    else           counts_sum[i - 32768] = s;
}

// ---------------- K3: finalize (single block, 1024 threads) ----------------
__global__ __launch_bounds__(1024) void k_final(const float* __restrict__ ema_cs,
                                                const float* __restrict__ ema_w,
                                                const float* __restrict__ counts,
                                                const float* __restrict__ dw,
                                                const float* __restrict__ loss_sum,
                                                float* __restrict__ out_loss,
                                                float* __restrict__ out_perp,
                                                float* __restrict__ out_emb,
                                                float* __restrict__ out_cs,
                                                float* __restrict__ out_ema_w) {
    int tid = threadIdx.x;
    __shared__ float s_cs[NUM_CODES];
    __shared__ float red[1024];

    float c = counts[tid];
    float pre = ema_cs[tid] * DECAYF + (1.0f - DECAYF) * c;

    red[tid] = pre;
    __syncthreads();
    for (int s = 512; s > 0; s >>= 1) {
        if (tid < s) red[tid] += red[tid + s];
        __syncthreads();
    }
    float n = red[0];
    __syncthreads();

    float ncs = (pre + EPSF) / (n + (float)NUM_CODES * EPSF) * n;
    s_cs[tid] = ncs;
    out_cs[tid] = ncs;

    float p = c / (float)ROWS;
    red[tid] = p * logf(p + 1e-10f);
    __syncthreads();
    for (int s = 512; s > 0; s >>= 1) {
        if (tid < s) red[tid] += red[tid + s];
        __syncthreads();
    }
    if (tid == 0) {
        out_perp[0] = expf(-red[0]);
        out_loss[0] = CCOST * (loss_sum[0] / (float)((size_t)ROWS * DIM));
    }
    __syncthreads();

    for (int i = tid; i < NUM_CODES * DIM; i += 1024) {
        int k = i >> 5;
        float w = ema_w[i] * DECAYF + (1.0f - DECAYF) * dw[i];
        out_ema_w[i] = w;
        out_emb[i] = w / s_cs[k];
    }
}

extern "C" void kernel_launch(void* const* d_in, const int* in_sizes, int n_in,
                              void* d_out, int out_size, void* d_ws, size_t ws_size,
                              hipStream_t stream) {
    const float* inputs    = (const float*)d_in[0];   // [16384,256]
    const float* embedding = (const float*)d_in[1];   // [1024,32]
    const float* ema_cs    = (const float*)d_in[2];   // [1024]
    const float* ema_w     = (const float*)d_in[3];   // [1024,32]

    // output layout (flat f32, return order)
    float* out        = (float*)d_out;
    float* out_loss   = out;                       // 1
    float* out_q      = out + 1;                   // 4194304
    float* out_perp   = out + 4194305;             // 1
    float* out_idxf   = out + 4194306;             // 131072
    float* out_emb    = out + 4325378;             // 32768
    float* out_cs     = out + 4358146;             // 1024
    float* out_ema_w  = out + 4359170;             // 32768

    // workspace layout (bytes)
    char* ws = (char*)d_ws;
    float* nneg       = (float*)(ws);                // 1024 f32   @ 0
    float* loss_sum   = (float*)(ws + 4096);         // 1 f32      @ 4096
    float* counts_sum = (float*)(ws + 8192);         // 1024 f32   @ 8192
    float* dw_sum     = (float*)(ws + 12288);        // 32768 f32  @ 12288 .. 143360
    unsigned short* bhi_g = (unsigned short*)(ws + 143360);  // 64 KB .. 208896
    unsigned short* blo_g = (unsigned short*)(ws + 208896);  // 64 KB .. 274432
    unsigned long long* part = (unsigned long long*)(ws + 274432); // 4 MB .. 4468736
    float* partial    = (float*)(ws + 4468736);      // 8*33792 f32 .. 5550080
    float* slabs      = (float*)(ws + 5550080);      // P * 33792 f32

    size_t slab_off = 5550080;
    size_t avail = (ws_size > slab_off) ? (ws_size - slab_off) : 0;
    int P = 16;
    if (avail >= (size_t)256 * SLAB * 4) P = 256;
    else if (avail >= (size_t)128 * SLAB * 4) P = 128;
    else if (avail >= (size_t)64 * SLAB * 4) P = 64;
    else if (avail >= (size_t)32 * SLAB * 4) P = 32;
    int rows_per_block = ROWS / P;

    k_prep   <<<16, 256, 0, stream>>>(embedding, bhi_g, blo_g, nneg, loss_sum);
    k_argmin <<<ROWS / 64, 256, 0, stream>>>(inputs, bhi_g, blo_g, nneg, part);
    k_scatter<<<P, 256, 0, stream>>>(inputs, embedding, part, out_q, out_idxf,
                                     slabs, loss_sum, rows_per_block);
    k_reduce1<<<RGROUPS * IBLK, 256, 0, stream>>>(slabs, partial, P / RGROUPS);
    k_reduce2<<<IBLK, 256, 0, stream>>>(partial, dw_sum, counts_sum);
    k_final  <<<1, 1024, 0, stream>>>(ema_cs, ema_w, counts_sum, dw_sum, loss_sum,
                                      out_loss, out_perp, out_emb, out_cs, out_ema_w);
}

// Round 6
// 100.955 us; speedup vs baseline: 3.9893x; 3.9893x over previous
//
#include <hip/hip_runtime.h>

#define NUM_CODES 1024
#define DIM 32
#define ROWS 131072      // 16384 * 8
#define DECAYF 0.99f
#define EPSF 1e-5f
#define CCOST 0.25f
#define SLAB 33792       // 32768 dw + 1024 counts
#define RGROUPS 8        // reduce stage-1 groups
#define IBLK (SLAB / 256)  // 132
#define TILES_PER_CHUNK 16
#define DBIAS 256.0f     // distance bias: keeps acc strictly negative

typedef __attribute__((ext_vector_type(8))) short short8v;
typedef __attribute__((ext_vector_type(4))) float f32x4;

__device__ __forceinline__ unsigned short bf16_rne(float f) {
    unsigned u = __float_as_uint(f);
    unsigned r = u + 0x7FFFu + ((u >> 16) & 1u);
    return (unsigned short)(r >> 16);
}

// ---------------- K0: prep — bf16 hi/lo B tables + biased norms + loss zero ----
// slot = tile*64 + lane; B-frag layout: col = lane&15 (code within tile),
// k = (lane>>4)*8 + j. Each slot stores 8 bf16 (16 B) in hi and lo tables.
// nbias[k] = -0.5||e_k||^2 - DBIAS  (acc = f.e + nbias < 0 always for this data)
__global__ __launch_bounds__(256) void k_prep(const float* __restrict__ emb,
                                              unsigned short* __restrict__ bhi,
                                              unsigned short* __restrict__ blo,
                                              float* __restrict__ nbias,
                                              float* __restrict__ loss_sum) {
    int s = blockIdx.x * 256 + threadIdx.x;   // 0..4095
    if (s == 0) loss_sum[0] = 0.0f;
    if (s < NUM_CODES) {
        const float4* e4 = (const float4*)(emb + s * DIM);
        float sum = 0.0f;
#pragma unroll
        for (int j = 0; j < 8; ++j) {
            float4 e = e4[j];
            sum += e.x * e.x + e.y * e.y + e.z * e.z + e.w * e.w;
        }
        nbias[s] = -0.5f * sum - DBIAS;
    }
    int l = s & 63, t = s >> 6;
    int code = t * 16 + (l & 15);
    int koff = (l >> 4) * 8;
    const float* src = emb + code * DIM + koff;
    float4 f0 = *(const float4*)(src);
    float4 f1 = *(const float4*)(src + 4);
    float fv[8] = {f0.x, f0.y, f0.z, f0.w, f1.x, f1.y, f1.z, f1.w};
    short8v h, lo;
#pragma unroll
    for (int j = 0; j < 8; ++j) {
        unsigned short hb = bf16_rne(fv[j]);
        float hf = __uint_as_float((unsigned)hb << 16);
        h[j]  = (short)hb;
        lo[j] = (short)bf16_rne(fv[j] - hf);
    }
    *(short8v*)(bhi + (size_t)s * 8) = h;
    *(short8v*)(blo + (size_t)s * 8) = lo;
}

// ---------------- K1: MFMA distance + argmin, codebook split across waves ----------
// Block = 4 waves, all owning the SAME 32 rows (A reads L1-shared);
// wave w scans tiles [w*16, w*16+16). acc = f.e - 0.5||e||^2 - 256 < 0 always,
// so raw-bit u32 min == argmax acc == argmin dist. Code packed into low 10
// mantissa bits: packed = (bits(acc) & ~1023) | code  (v_bfi + v_min_u32).
// C/D layout (m89-verified): col = lane&15, row = (lane>>4)*4 + reg.
__global__ __launch_bounds__(256) void k_argmin(const float* __restrict__ flat,
                                                const unsigned short* __restrict__ bhi_g,
                                                const unsigned short* __restrict__ blo_g,
                                                const float* __restrict__ nbias,
                                                unsigned* __restrict__ part) {
    const int lane = threadIdx.x & 63;
    const int wid  = threadIdx.x >> 6;       // chunk 0..3
    const int rowbase = blockIdx.x * 32;
    const int lr = lane & 15;   // A row / B,C col within frag
    const int lg = lane >> 4;   // k-group

    // load + hi/lo split A (2 row-frags, 32 rows)
    short8v ahi[2], alo[2];
#pragma unroll
    for (int rf = 0; rf < 2; ++rf) {
        const float* src = flat + (size_t)(rowbase + rf * 16 + lr) * DIM + lg * 8;
        float4 f0 = *(const float4*)src;
        float4 f1 = *(const float4*)(src + 4);
        float fv[8] = {f0.x, f0.y, f0.z, f0.w, f1.x, f1.y, f1.z, f1.w};
        short8v h, lo;
#pragma unroll
        for (int j = 0; j < 8; ++j) {
            unsigned short hb = bf16_rne(fv[j]);
            float hf = __uint_as_float((unsigned)hb << 16);
            h[j]  = (short)hb;
            lo[j] = (short)bf16_rne(fv[j] - hf);
        }
        ahi[rf] = h; alo[rf] = lo;
    }

    unsigned best[2][4];
#pragma unroll
    for (int rf = 0; rf < 2; ++rf)
#pragma unroll
        for (int rg = 0; rg < 4; ++rg) best[rf][rg] = 0xFFFFFFFFu;

    const int t0 = wid * TILES_PER_CHUNK;
#pragma unroll 2
    for (int tt = 0; tt < TILES_PER_CHUNK; ++tt) {
        const int t = t0 + tt;
        short8v bh = *(const short8v*)(bhi_g + ((size_t)t * 64 + lane) * 8);
        short8v bl = *(const short8v*)(blo_g + ((size_t)t * 64 + lane) * 8);
        float nn = nbias[t * 16 + lr];
        unsigned code = (unsigned)(t * 16 + lr);
#pragma unroll
        for (int rf = 0; rf < 2; ++rf) {
            f32x4 acc = {nn, nn, nn, nn};
            acc = __builtin_amdgcn_mfma_f32_16x16x32_bf16(ahi[rf], bh, acc, 0, 0, 0);
            acc = __builtin_amdgcn_mfma_f32_16x16x32_bf16(ahi[rf], bl, acc, 0, 0, 0);
            acc = __builtin_amdgcn_mfma_f32_16x16x32_bf16(alo[rf], bh, acc, 0, 0, 0);
#pragma unroll
            for (int rg = 0; rg < 4; ++rg) {
                unsigned pb = (__float_as_uint(acc[rg]) & 0xFFFFFC00u) | code;
                best[rf][rg] = min(best[rf][rg], pb);
            }
        }
    }

    // u32-min reduce across the 16-lane group (codes live across lane&15)
#pragma unroll
    for (int rf = 0; rf < 2; ++rf) {
#pragma unroll
        for (int rg = 0; rg < 4; ++rg) {
            unsigned b = best[rf][rg];
#pragma unroll
            for (int m = 1; m < 16; m <<= 1)
                b = min(b, (unsigned)__shfl_xor((int)b, m));
            if (lr == rg)
                part[(size_t)wid * ROWS + rowbase + rf * 16 + lg * 4 + rg] = b;
        }
    }
}

// ---------------- K2: combine argmin, gather/quantize, loss; LDS counts/dw ---------
__global__ __launch_bounds__(256) void k_scatter(const float* __restrict__ flat,
                                                 const float* __restrict__ emb,
                                                 const unsigned* __restrict__ part,
                                                 float* __restrict__ qout,
                                                 float* __restrict__ idxf_out,
                                                 float* __restrict__ slabs,
                                                 float* __restrict__ loss_sum,
                                                 int rows_per_block) {
    __shared__ float acc[SLAB];   // 132 KB
    __shared__ float red[256];
    const int tid = threadIdx.x;
    for (int i = tid; i < SLAB; i += 256) acc[i] = 0.0f;
    __syncthreads();

    const int row0 = blockIdx.x * rows_per_block;
    float l = 0.0f;
    for (int rr = 0; rr < rows_per_block; rr += 256) {
        int r = row0 + rr + tid;
        unsigned p0 = part[r];
        unsigned p1 = part[(size_t)ROWS + r];
        unsigned p2 = part[2 * (size_t)ROWS + r];
        unsigned p3 = part[3 * (size_t)ROWS + r];
        unsigned pm = min(min(p0, p1), min(p2, p3));
        int k = (int)(pm & 1023u);
        idxf_out[r] = (float)k;

        const float4* f4 = (const float4*)(flat + (size_t)r * DIM);
        const float4* e4 = (const float4*)(emb + (size_t)k * DIM);
        float4* q4 = (float4*)(qout + (size_t)r * DIM);
        int kb = k * DIM;
#pragma unroll
        for (int j4 = 0; j4 < 8; ++j4) {
            float4 f = f4[j4];
            float4 e = e4[j4];
            q4[j4] = e;
            float dx = e.x - f.x, dy = e.y - f.y, dz = e.z - f.z, dv = e.w - f.w;
            l += dx * dx + dy * dy + dz * dz + dv * dv;
            int j = 4 * j4;
            // swizzled LDS layout: entry (k,j) lives at k*32 + ((j+k)&31)
            atomicAdd(&acc[kb + ((j + 0 + k) & 31)], f.x);
            atomicAdd(&acc[kb + ((j + 1 + k) & 31)], f.y);
            atomicAdd(&acc[kb + ((j + 2 + k) & 31)], f.z);
            atomicAdd(&acc[kb + ((j + 3 + k) & 31)], f.w);
        }
        atomicAdd(&acc[32768 + k], 1.0f);
    }
    __syncthreads();

    // flush LDS -> per-block slab (un-swizzle; coalesced global writes)
    float* slab = slabs + (size_t)blockIdx.x * SLAB;
    for (int i = tid; i < 32768; i += 256) {
        int k = i >> 5, j = i & 31;
        slab[i] = acc[(i & ~31) | ((j + k) & 31)];
    }
    for (int i = tid; i < NUM_CODES; i += 256) slab[32768 + i] = acc[32768 + i];

    red[tid] = l;
    __syncthreads();
    for (int s = 128; s > 0; s >>= 1) {
        if (tid < s) red[tid] += red[tid + s];
        __syncthreads();
    }
    if (tid == 0) atomicAdd(loss_sum, red[0]);
}

// ---------------- K2b: two-stage slab reduction ----------------
__global__ __launch_bounds__(256) void k_reduce1(const float* __restrict__ slabs,
                                                 float* __restrict__ partial,
                                                 int pcount) {
    int g  = blockIdx.x / IBLK;
    int ib = blockIdx.x % IBLK;
    int i = ib * 256 + threadIdx.x;
    const float* base = slabs + (size_t)g * pcount * SLAB + i;
    float s = 0.0f;
#pragma unroll 4
    for (int p = 0; p < pcount; ++p) s += base[(size_t)p * SLAB];
    partial[(size_t)g * SLAB + i] = s;
}

__global__ __launch_bounds__(256) void k_reduce2(const float* __restrict__ partial,
                                                 float* __restrict__ dw_sum,
                                                 float* __restrict__ counts_sum) {
    int i = blockIdx.x * 256 + threadIdx.x;
    float s = 0.0f;
#pragma unroll
    for (int g = 0; g < RGROUPS; ++g) s += partial[(size_t)g * SLAB + i];
    if (i < 32768) dw_sum[i] = s;
    else           counts_sum[i - 32768] = s;
}

// ---------------- K3: finalize (single block, 1024 threads) ----------------
__global__ __launch_bounds__(1024) void k_final(const float* __restrict__ ema_cs,
                                                const float* __restrict__ ema_w,
                                                const float* __restrict__ counts,
                                                const float* __restrict__ dw,
                                                const float* __restrict__ loss_sum,
                                                float* __restrict__ out_loss,
                                                float* __restrict__ out_perp,
                                                float* __restrict__ out_emb,
                                                float* __restrict__ out_cs,
                                                float* __restrict__ out_ema_w) {
    int tid = threadIdx.x;
    __shared__ float s_cs[NUM_CODES];
    __shared__ float red[1024];

    float c = counts[tid];
    float pre = ema_cs[tid] * DECAYF + (1.0f - DECAYF) * c;

    red[tid] = pre;
    __syncthreads();
    for (int s = 512; s > 0; s >>= 1) {
        if (tid < s) red[tid] += red[tid + s];
        __syncthreads();
    }
    float n = red[0];
    __syncthreads();

    float ncs = (pre + EPSF) / (n + (float)NUM_CODES * EPSF) * n;
    s_cs[tid] = ncs;
    out_cs[tid] = ncs;

    float p = c / (float)ROWS;
    red[tid] = p * logf(p + 1e-10f);
    __syncthreads();
    for (int s = 512; s > 0; s >>= 1) {
        if (tid < s) red[tid] += red[tid + s];
        __syncthreads();
    }
    if (tid == 0) {
        out_perp[0] = expf(-red[0]);
        out_loss[0] = CCOST * (loss_sum[0] / (float)((size_t)ROWS * DIM));
    }
    __syncthreads();

    for (int i = tid; i < NUM_CODES * DIM; i += 1024) {
        int k = i >> 5;
        float w = ema_w[i] * DECAYF + (1.0f - DECAYF) * dw[i];
        out_ema_w[i] = w;
        out_emb[i] = w / s_cs[k];
    }
}

extern "C" void kernel_launch(void* const* d_in, const int* in_sizes, int n_in,
                              void* d_out, int out_size, void* d_ws, size_t ws_size,
                              hipStream_t stream) {
    const float* inputs    = (const float*)d_in[0];   // [16384,256]
    const float* embedding = (const float*)d_in[1];   // [1024,32]
    const float* ema_cs    = (const float*)d_in[2];   // [1024]
    const float* ema_w     = (const float*)d_in[3];   // [1024,32]

    // output layout (flat f32, return order)
    float* out        = (float*)d_out;
    float* out_loss   = out;                       // 1
    float* out_q      = out + 1;                   // 4194304
    float* out_perp   = out + 4194305;             // 1
    float* out_idxf   = out + 4194306;             // 131072
    float* out_emb    = out + 4325378;             // 32768
    float* out_cs     = out + 4358146;             // 1024
    float* out_ema_w  = out + 4359170;             // 32768

    // workspace layout (bytes)
    char* ws = (char*)d_ws;
    float* nbias      = (float*)(ws);                // 1024 f32   @ 0
    float* loss_sum   = (float*)(ws + 4096);         // 1 f32      @ 4096
    float* counts_sum = (float*)(ws + 8192);         // 1024 f32   @ 8192
    float* dw_sum     = (float*)(ws + 12288);        // 32768 f32  @ 12288 .. 143360
    unsigned short* bhi_g = (unsigned short*)(ws + 143360);  // 64 KB .. 208896
    unsigned short* blo_g = (unsigned short*)(ws + 208896);  // 64 KB .. 274432
    unsigned* part    = (unsigned*)(ws + 274432);    // 4*131072 u32 = 2 MB .. 2371584
    float* partial    = (float*)(ws + 2371584);      // 8*33792 f32 .. 3452928
    float* slabs      = (float*)(ws + 3452928);      // P * 33792 f32

    size_t slab_off = 3452928;
    size_t avail = (ws_size > slab_off) ? (ws_size - slab_off) : 0;
    int P = 16;
    if (avail >= (size_t)256 * SLAB * 4) P = 256;
    else if (avail >= (size_t)128 * SLAB * 4) P = 128;
    else if (avail >= (size_t)64 * SLAB * 4) P = 64;
    else if (avail >= (size_t)32 * SLAB * 4) P = 32;
    int rows_per_block = ROWS / P;

    k_prep   <<<16, 256, 0, stream>>>(embedding, bhi_g, blo_g, nbias, loss_sum);
    k_argmin <<<ROWS / 32, 256, 0, stream>>>(inputs, bhi_g, blo_g, nbias, part);
    k_scatter<<<P, 256, 0, stream>>>(inputs, embedding, part, out_q, out_idxf,
                                     slabs, loss_sum, rows_per_block);
    k_reduce1<<<RGROUPS * IBLK, 256, 0, stream>>>(slabs, partial, P / RGROUPS);
    k_reduce2<<<IBLK, 256, 0, stream>>>(partial, dw_sum, counts_sum);
    k_final  <<<1, 1024, 0, stream>>>(ema_cs, ema_w, counts_sum, dw_sum, loss_sum,
                                      out_loss, out_perp, out_emb, out_cs, out_ema_w);
}